// Round 5
// baseline (2979.187 us; speedup 1.0000x reference)
//
#include <hip/hip_runtime.h>
#include <stdint.h>

typedef unsigned short u16;
typedef unsigned int u32;
typedef unsigned long long u64;
typedef __attribute__((ext_vector_type(4))) float f32x4;
typedef __attribute__((ext_vector_type(8))) short bf16x8;
typedef __attribute__((ext_vector_type(4))) u32 u32x4;

constexpr int kT = 8192;   // sequence length
constexpr int kD = 512;    // word emb dim
constexpr int kH = 2048;   // hidden
constexpr int kH3 = 6144;  // 3*H
constexpr int kS = 512;    // segments
constexpr int kSeg = 16;   // tokens per segment
constexpr int kNWG2 = 256; // persistent WGs for upper GRU
constexpr int kREP = 4;    // h-exchange replicas

__device__ __forceinline__ float bf2f(u16 u) {
  union { float f; u32 u; } v; v.u = ((u32)u) << 16; return v.f;
}
__device__ __forceinline__ u16 f2bf(float f) {
  union { float f; u32 u; } v; v.f = f;
  u32 lsb = (v.u >> 16) & 1u;
  v.u += 0x7fffu + lsb;          // round-to-nearest-even
  return (u16)(v.u >> 16);
}
// cheap packed-bf16 unpack: lo/hi half of a u32 as f32 (2 ops each)
__device__ __forceinline__ float bflo(u32 x) {
  union { float f; u32 u; } v; v.u = x << 16; return v.f;
}
__device__ __forceinline__ float bfhi(u32 x) {
  union { float f; u32 u; } v; v.u = x & 0xffff0000u; return v.f;
}
__device__ __forceinline__ float sigm(float x) { return 1.f / (1.f + expf(-x)); }

// async global->LDS, 16B per lane; LDS dest = wave-uniform base + lane*16
__device__ __forceinline__ void g2l16(const u16* g, u16* l) {
  __builtin_amdgcn_global_load_lds(
      (const __attribute__((address_space(1))) u32*)g,
      (__attribute__((address_space(3))) u32*)l, 16, 0, 0);
}

// device-coherent (sc0 sc1) 16B bypass load/store: same coherence as relaxed
// agent atomics, but plain -> coalesces in the TA (1 transaction per line).
// ext_vector operands (NOT HIP's struct uint4) so asm 'v' maps a VGPR quad.
__device__ __forceinline__ u32x4 bypass_load16(const u32* p) {
  u32x4 v;
  asm volatile("global_load_dwordx4 %0, %1, off sc0 sc1\n\ts_waitcnt vmcnt(0)"
               : "=&v"(v) : "v"(p) : "memory");
  return v;
}
__device__ __forceinline__ void bypass_store16(u32* p, u32x4 v) {
  asm volatile("global_store_dwordx4 %0, %1, off sc0 sc1" :: "v"(p), "v"(v) : "memory");
}

// ---------------- f32 -> bf16 convert ----------------
__global__ void cvt_bf16(const float* __restrict__ in, u16* __restrict__ out, int n4) {
  int i = blockIdx.x * blockDim.x + threadIdx.x;
  if (i >= n4) return;
  const float4 v = *(const float4*)(in + (size_t)i * 4);
  uint2 o;
  o.x = (u32)f2bf(v.x) | ((u32)f2bf(v.y) << 16);
  o.y = (u32)f2bf(v.z) | ((u32)f2bf(v.w) << 16);
  *(uint2*)(out + (size_t)i * 4) = o;
}

// ---------------- bf16 GEMM  C = A(MxK,lda) * B(NxK,ldb)^T ----------------
// 4-deep software-pipelined staging (counted vmcnt + raw s_barrier; never
// drain-0 mid-loop). EPI 1: Obf = bf16(acc)   EPI 2: Obf = bf16(tanh(acc+bias))
template<int EPI>
__global__ __launch_bounds__(256)
void gemm_bt(const u16* __restrict__ A, int lda,
             const u16* __restrict__ B, int ldb,
             u16* __restrict__ Obf, const float* __restrict__ bias,
             int M, int N, int K)
{
  __shared__ u16 ls[4 * 16384];   // 4 bufs x (A 128x64 + B 128x64) = 128 KiB
  const int tid = threadIdx.x;
  const int w = tid >> 6, lane = tid & 63;
  const int wr = w >> 1, wc = w & 1;
  const int arow0 = blockIdx.y * 128;
  const int brow0 = blockIdx.x * 128;
  const int srow = w * 32 + (lane >> 3);
  const int scol = (lane & 7) * 8;
  const u16* gA = A + (size_t)(arow0 + srow) * lda + scol;
  const u16* gB = B + (size_t)(brow0 + srow) * ldb + scol;
  const int sb = w * 32 * 64;     // wave's staging base (rows w*32..)

  f32x4 acc[4][4];
#pragma unroll
  for (int m = 0; m < 4; ++m)
#pragma unroll
    for (int n = 0; n < 4; ++n) acc[m][n] = (f32x4)0.f;

  const int fr = lane & 15;
  const int kq = lane >> 4;
  const int nk = K >> 6;

  auto stage = [&](int buf, int kt) {
    u16* la = &ls[buf * 16384 + sb];
    u16* lb = &ls[buf * 16384 + 8192 + sb];
#pragma unroll
    for (int i = 0; i < 4; ++i) g2l16(gA + (size_t)i * 8 * lda + kt, la + i * 8 * 64);
#pragma unroll
    for (int i = 0; i < 4; ++i) g2l16(gB + (size_t)i * 8 * ldb + kt, lb + i * 8 * 64);
  };

  stage(0, 0);
  if (nk > 1) stage(1, 64);
  if (nk > 2) stage(2, 128);

  for (int i = 0; i < nk; ++i) {
    if (i + 2 < nk) asm volatile("s_waitcnt vmcnt(16)" ::: "memory");
    else            asm volatile("s_waitcnt vmcnt(0)" ::: "memory");
    __builtin_amdgcn_s_barrier();
    __builtin_amdgcn_sched_barrier(0);
    if (i + 3 < nk) stage((i + 3) & 3, (i + 3) * 64);
    const u16* lsA = &ls[(i & 3) * 16384];
    const u16* lsB = lsA + 8192;
#pragma unroll
    for (int kk = 0; kk < 2; ++kk) {
      bf16x8 af[4], bq[4];
#pragma unroll
      for (int m = 0; m < 4; ++m)
        af[m] = *(const bf16x8*)&lsA[(wr * 64 + m * 16 + fr) * 64 + kk * 32 + kq * 8];
#pragma unroll
      for (int n = 0; n < 4; ++n)
        bq[n] = *(const bf16x8*)&lsB[(wc * 64 + n * 16 + fr) * 64 + kk * 32 + kq * 8];
#pragma unroll
      for (int m = 0; m < 4; ++m)
#pragma unroll
        for (int n = 0; n < 4; ++n)
          acc[m][n] = __builtin_amdgcn_mfma_f32_16x16x32_bf16(af[m], bq[n], acc[m][n], 0, 0, 0);
    }
  }

#pragma unroll
  for (int m = 0; m < 4; ++m) {
#pragma unroll
    for (int n = 0; n < 4; ++n) {
      const int row0 = arow0 + wr * 64 + m * 16 + kq * 4;
      const int col = brow0 + wc * 64 + n * 16 + fr;
      if (EPI == 1) {
#pragma unroll
        for (int i = 0; i < 4; ++i)
          Obf[(size_t)(row0 + i) * N + col] = f2bf(acc[m][n][i]);
      } else {
        const float bv = bias[col];
#pragma unroll
        for (int i = 0; i < 4; ++i)
          Obf[(size_t)(row0 + i) * N + col] = f2bf(tanhf(acc[m][n][i] + bv));
      }
    }
  }
}

// ---------------- lower-GRU gates, paired-u32 bf16 I/O ----------------
__global__ __launch_bounds__(256) void gru1_gates(
    const u16* __restrict__ gi, const u16* __restrict__ gh,
    const float* __restrict__ bi, const float* __restrict__ bh,
    u16* __restrict__ h_bf, u16* __restrict__ outs_bf, int t)
{
  const int idx = blockIdx.x * 256 + threadIdx.x;  // 512*1024 pairs
  const int seg = idx >> 10, jp = idx & 1023;      // j = 2*jp
  const u32* gi32 = (const u32*)gi;
  const u32* gh32 = (const u32*)gh;
  const int base = seg * 3072;
  const u32 gir = gi32[base + jp],        ghr = gh32[base + jp];
  const u32 giz = gi32[base + 1024 + jp], ghz = gh32[base + 1024 + jp];
  const u32 gin = gi32[base + 2048 + jp], ghn = gh32[base + 2048 + jp];
  const float2 bir = *(const float2*)&bi[2 * jp];
  const float2 biz = *(const float2*)&bi[kH + 2 * jp];
  const float2 bin = *(const float2*)&bi[2 * kH + 2 * jp];
  const float2 bhr = *(const float2*)&bh[2 * jp];
  const float2 bhz = *(const float2*)&bh[kH + 2 * jp];
  const float2 bhn = *(const float2*)&bh[2 * kH + 2 * jp];
  const u32 hp = ((const u32*)h_bf)[seg * 1024 + jp];
  float hn[2];
#pragma unroll
  for (int e = 0; e < 2; ++e) {
    const float gr = e ? bfhi(gir) : bflo(gir), hr = e ? bfhi(ghr) : bflo(ghr);
    const float gz = e ? bfhi(giz) : bflo(giz), hz = e ? bfhi(ghz) : bflo(ghz);
    const float gn = e ? bfhi(gin) : bflo(gin), hh = e ? bfhi(ghn) : bflo(ghn);
    const float r = sigm(gr + (e ? bir.y : bir.x) + hr + (e ? bhr.y : bhr.x));
    const float z = sigm(gz + (e ? biz.y : biz.x) + hz + (e ? bhz.y : bhz.x));
    const float n = tanhf(gn + (e ? bin.y : bin.x) + r * (hh + (e ? bhn.y : bhn.x)));
    const float hprev = e ? bfhi(hp) : bflo(hp);
    hn[e] = (1.f - z) * n + z * hprev;
  }
  const u32 packed = (u32)f2bf(hn[0]) | ((u32)f2bf(hn[1]) << 16);
  ((u32*)h_bf)[seg * 1024 + jp] = packed;
  ((u32*)outs_bf)[(size_t)(seg * kSeg + t) * 1024 + jp] = packed;
}

// ---------------- degenerate softmax weight + per-segment column max ----------------
__global__ __launch_bounds__(256) void seg_weight_max(
    const u16* __restrict__ embh, const float* __restrict__ wa,
    u16* __restrict__ seg_bf)
{
  __shared__ float wrow[16];
  const int s = blockIdx.x, tid = threadIdx.x;
  const int w = tid >> 6, lane = tid & 63;
#pragma unroll
  for (int rr = 0; rr < 4; ++rr) {
    const int r = w * 4 + rr;
    const u16* row = embh + ((size_t)s * kSeg + r) * kH;
    float p = 0.f;
#pragma unroll
    for (int k = 0; k < 32; ++k) {
      const int c = lane + 64 * k;
      p += bf2f(row[c]) * wa[c];
    }
#pragma unroll
    for (int off = 32; off; off >>= 1) p += __shfl_down(p, off, 64);
    if (lane == 0) { const float e = expf(p); wrow[r] = e / (e + 1e-4f); }
  }
  __syncthreads();
#pragma unroll
  for (int i = 0; i < 8; ++i) {
    const int c = tid + 256 * i;
    float m = -1e30f;
#pragma unroll
    for (int r = 0; r < 16; ++r)
      m = fmaxf(m, wrow[r] * bf2f(embh[((size_t)s * kSeg + r) * kH + c]));
    seg_bf[(size_t)s * kH + c] = f2bf(m);
  }
}

// ---------------- upper GRU: persistent, 512 steps -------------------------
// SELF-VALIDATING exchange words: u32 = (bf16 << 16) | step_tag (t fits 16b).
// No tearing hazard at any store granularity -> plain coalescable sc0/sc1
// bypass loads/stores replace per-word atomics (8x fewer fabric transactions).
// Consumer polls its own 16B quad; equality tag check; wave-level retry.
// Slot reuse safety: writer of tag t+2 implies all WGs consumed tag-t slot
// (monotonic-tag argument), and parity slots only ever hold tags {t, t-2,..}
// so equality distinguishes fresh from stale. hx memset per launch keeps
// graph replays deterministic.
__global__ __launch_bounds__(512)
void gru2_persistent(const u16* __restrict__ Wh2bf, const u16* __restrict__ gi2b,
                     const float* __restrict__ bi2, const float* __restrict__ bh2,
                     u32* __restrict__ hx,        // [2][kREP][2048] tagged u32
                     u16* __restrict__ outs2)     // 512*2048 bf16
{
  __shared__ u16 wl[24 * kH];                 // 96 KiB weights (24 rows)
  __shared__ u32 hlb[1024];                   // 4 KiB: h as packed bf16 pairs
  __shared__ float gil_all[512 * 24];         // 48 KiB gi2 slice
  __shared__ float rowsum[24];
  __shared__ alignas(16) u16 hnl[8];
  const int wg = blockIdx.x, tid = threadIdx.x;
  const int g0 = wg * 8;
  const int rep = wg & (kREP - 1);
  // weights: 24 rows x 256 uint4
  uint4* wl4 = (uint4*)wl;
  for (int i = tid; i < 24 * 256; i += 512) {
    const int lr = i >> 8, q = i & 255;
    const int grow = (lr >> 3) * kH + g0 + (lr & 7);
    wl4[i] = ((const uint4*)Wh2bf)[(size_t)grow * 256 + q];
  }
  for (int i = tid; i < 512 * 24; i += 512) {
    const int t = i / 24, idx = i - t * 24;
    gil_all[i] = bf2f(gi2b[(size_t)t * kH3 + (idx >> 3) * kH + g0 + (idx & 7)]);
  }
  float bir = 0, biz = 0, bin = 0, bhr = 0, bhz = 0, bhn = 0;
  if (tid < 8) {
    const int jj = g0 + tid;
    bir = bi2[jj]; biz = bi2[kH + jj]; bin = bi2[2 * kH + jj];
    bhr = bh2[jj]; bhz = bh2[kH + jj]; bhn = bh2[2 * kH + jj];
  }
  const int w = tid >> 6, lane = tid & 63;
  const uint4* hl4 = (const uint4*)hlb;

  for (int t = 0; t < 512; ++t) {
    // ---- poll-in: one 16B bypass load per thread, embedded-tag check ----
    const u32 want = (u32)t & 0xffffu;
    const u32* p = hx + ((size_t)(t & 1) * kREP + rep) * 2048 + 4 * tid;
    u32x4 v;
    for (;;) {
      v = bypass_load16(p);
      const u32 bad = ((v.x ^ want) | (v.y ^ want) | (v.z ^ want) | (v.w ^ want)) & 0xffffu;
      if (!__any((int)bad)) break;
      __builtin_amdgcn_s_sleep(1);
    }
    hlb[2 * tid]     = (v.x >> 16) | (v.y & 0xffff0000u);
    hlb[2 * tid + 1] = (v.z >> 16) | (v.w & 0xffff0000u);
    __syncthreads();
    // ---- matvec: 3 rows per wave, uint4 LDS reads, 2-op unpack ----
#pragma unroll
    for (int rr = 0; rr < 3; ++rr) {
      const int lr = w * 3 + rr;
      float p2 = 0.f;
#pragma unroll
      for (int k = 0; k < 4; ++k) {
        const int q = lane + 64 * k;
        const uint4 wv = wl4[lr * 256 + q];
        const uint4 hv = hl4[q];
        p2 += bflo(wv.x) * bflo(hv.x) + bfhi(wv.x) * bfhi(hv.x);
        p2 += bflo(wv.y) * bflo(hv.y) + bfhi(wv.y) * bfhi(hv.y);
        p2 += bflo(wv.z) * bflo(hv.z) + bfhi(wv.z) * bfhi(hv.z);
        p2 += bflo(wv.w) * bflo(hv.w) + bfhi(wv.w) * bfhi(hv.w);
      }
#pragma unroll
      for (int off = 32; off; off >>= 1) p2 += __shfl_down(p2, off, 64);
      if (lane == 0) rowsum[lr] = p2;
    }
    __syncthreads();
    // ---- gates ----
    if (tid < 8) {
      const float r = sigm(gil_all[t * 24 + tid] + bir + rowsum[tid] + bhr);
      const float z = sigm(gil_all[t * 24 + 8 + tid] + biz + rowsum[8 + tid] + bhz);
      const float n = tanhf(gil_all[t * 24 + 16 + tid] + bin +
                            r * (rowsum[16 + tid] + bhn));
      const u32 hw = hlb[(g0 + tid) >> 1];
      const float hprev = (tid & 1) ? bfhi(hw) : bflo(hw);
      hnl[tid] = f2bf((1.f - z) * n + z * hprev);
    }
    __syncthreads();
    // ---- tagged broadcast-out: 2 x 16B per replica, 8 threads total ----
    if (tid < 2 * kREP) {
      const int orep = tid >> 1, half = tid & 1;
      const u16* h4 = hnl + half * 4;
      const u32 tagv = (u32)(t + 1) & 0xffffu;
      u32x4 m;
      m.x = ((u32)h4[0] << 16) | tagv;
      m.y = ((u32)h4[1] << 16) | tagv;
      m.z = ((u32)h4[2] << 16) | tagv;
      m.w = ((u32)h4[3] << 16) | tagv;
      u32* q = hx + ((size_t)((t + 1) & 1) * kREP + orep) * 2048 + wg * 8 + half * 4;
      bypass_store16(q, m);
    }
    if (tid == 0)
      *(uint4*)&outs2[(size_t)t * kH + g0] = *(const uint4*)hnl;
  }
}

// ---------------- w2 then final column max ----------------
__global__ void calc_w2(const u16* __restrict__ e2, const float* __restrict__ wa2,
                        float* __restrict__ w2) {
  const int s = blockIdx.x, lane = threadIdx.x;  // 64 threads
  float p = 0.f;
#pragma unroll
  for (int k = 0; k < 32; ++k) {
    const int c = lane + 64 * k;
    p += bf2f(e2[(size_t)s * kH + c]) * wa2[c];
  }
#pragma unroll
  for (int off = 32; off; off >>= 1) p += __shfl_down(p, off, 64);
  if (lane == 0) { const float e = expf(p); w2[s] = e / (e + 1e-4f); }
}

__global__ void final_max(const u16* __restrict__ e2, const float* __restrict__ w2,
                          float* __restrict__ out) {
  const int j = blockIdx.x * blockDim.x + threadIdx.x;  // 2048
  float m = -1e30f;
  for (int s = 0; s < 512; ++s)
    m = fmaxf(m, w2[s] * bf2f(e2[(size_t)s * kH + j]));
  out[j] = m;
}

// ---------------- host ----------------
extern "C" void kernel_launch(void* const* d_in, const int* in_sizes, int n_in,
                              void* d_out, int out_size, void* d_ws, size_t ws_size,
                              hipStream_t stream)
{
  (void)in_sizes; (void)n_in; (void)out_size; (void)ws_size;
  const float* sent = (const float*)d_in[0];
  const float* Wi1f = (const float*)d_in[1];
  const float* Wh1f = (const float*)d_in[2];
  const float* bi1  = (const float*)d_in[3];
  const float* bh1  = (const float*)d_in[4];
  const float* Wi2f = (const float*)d_in[5];
  const float* Wh2f = (const float*)d_in[6];
  const float* bi2  = (const float*)d_in[7];
  const float* bh2  = (const float*)d_in[8];
  const float* Wlf  = (const float*)d_in[9];
  const float* bl   = (const float*)d_in[10];
  const float* wa   = (const float*)d_in[11];
  const float* Wl2f = (const float*)d_in[12];
  const float* bl2  = (const float*)d_in[13];
  const float* wa2  = (const float*)d_in[14];
  float* out = (float*)d_out;

  char* base = (char*)d_ws;
  size_t off = 0;
  auto alloc = [&](size_t b) { char* p = base + off; off += (b + 255) & ~(size_t)255; return p; };
  u16* sent_bf = (u16*)alloc((size_t)kT * kD * 2);   // dead after phase B -> embh alias
  u16* Wi1b    = (u16*)alloc((size_t)kH3 * kD * 2);
  u16* Wh1b    = (u16*)alloc((size_t)kH3 * kH * 2);
  u16* Wi2b    = (u16*)alloc((size_t)kH3 * kH * 2);
  u16* Wh2b    = (u16*)alloc((size_t)kH3 * kH * 2);
  u16* Wlb     = (u16*)alloc((size_t)kH * kH * 2);
  u16* Wl2b    = (u16*)alloc((size_t)kH * kH * 2);
  u16* gi_buf  = (u16*)alloc((size_t)kS * kH3 * 2);  // bf16
  u16* gh_buf  = (u16*)alloc((size_t)kS * kH3 * 2);
  u16* h1b     = (u16*)alloc((size_t)kS * kH * 2);
  u16* outs_bf = (u16*)alloc((size_t)kT * kH * 2);
  u16* seg_bf  = (u16*)alloc((size_t)kS * kH * 2);
  u32* hx      = (u32*)alloc((size_t)2 * kREP * 2048 * 4);
  u16* outs2   = (u16*)alloc((size_t)kS * kH * 2);
  u16* e2b     = (u16*)alloc((size_t)kS * kH * 2);
  float* w2    = (float*)alloc(kS * 4);
  // aliases over dead regions
  u16* embh = sent_bf;   // 33.5 MB fits in sent_bf+Wi1b+Wh1b (39.8 MB)
  u16* gi2b = gi_buf;

  (void)hipMemsetAsync(h1b, 0, (size_t)kS * kH * 2, stream);
  (void)hipMemsetAsync(hx, 0, (size_t)2 * kREP * 2048 * 4, stream);

  auto cvt = [&](const float* src, u16* dst, int n) {
    const int n4 = n / 4;
    cvt_bf16<<<dim3((n4 + 255) / 256), dim3(256), 0, stream>>>(src, dst, n4);
  };
  cvt(sent, sent_bf, kT * kD);
  cvt(Wi1f, Wi1b, kH3 * kD);
  cvt(Wh1f, Wh1b, kH3 * kH);
  cvt(Wi2f, Wi2b, kH3 * kH);
  cvt(Wlf, Wlb, kH * kH);
  cvt(Wl2f, Wl2b, kH * kH);
  cvt(Wh2f, Wh2b, kH3 * kH);

  // ---- phase B: lower GRU, 16 batched steps over 512 independent chains ----
  for (int t = 0; t < kSeg; ++t) {
    gemm_bt<1><<<dim3(kH3 / 128, kS / 128), dim3(256), 0, stream>>>(
        h1b, kH, Wh1b, kH, gh_buf, nullptr, kS, kH3, kH);
    gemm_bt<1><<<dim3(kH3 / 128, kS / 128), dim3(256), 0, stream>>>(
        sent_bf + t * kD, kSeg * kD, Wi1b, kD, gi_buf, nullptr, kS, kH3, kD);
    gru1_gates<<<dim3(kS * kH / 512), dim3(256), 0, stream>>>(
        gi_buf, gh_buf, bi1, bh1, h1b, outs_bf, t);
  }
  // ---- phase C: emb_h = tanh(outs @ Wl^T + bl) ----
  gemm_bt<2><<<dim3(kH / 128, kT / 128), dim3(256), 0, stream>>>(
      outs_bf, kH, Wlb, kH, embh, bl, kT, kH, kH);
  // ---- phase D: w, weighted, segment max ----
  seg_weight_max<<<dim3(kS), dim3(256), 0, stream>>>(embh, wa, seg_bf);
  // ---- phase E: gi2 = seg @ Wi2^T (bf16) ----
  gemm_bt<1><<<dim3(kH3 / 128, kS / 128), dim3(256), 0, stream>>>(
      seg_bf, kH, Wi2b, kH, gi2b, nullptr, kS, kH3, kH);
  // ---- phase F: upper GRU, 512 sequential steps, self-validating exchange ----
  gru2_persistent<<<dim3(kNWG2), dim3(512), 0, stream>>>(
      Wh2b, gi2b, bi2, bh2, hx, outs2);
  // ---- phase G: e2 = tanh(outs2 @ Wl2^T + bl2), w2, final max ----
  gemm_bt<2><<<dim3(kH / 128, kS / 128), dim3(256), 0, stream>>>(
      outs2, kH, Wl2b, kH, e2b, bl2, kS, kH, kH);
  calc_w2<<<dim3(kS), dim3(64), 0, stream>>>(e2b, wa2, w2);
  final_max<<<dim3(kH / 256), dim3(256), 0, stream>>>(e2b, w2, out);
}

// Round 6
// 2972.044 us; speedup vs baseline: 1.0024x; 1.0024x over previous
//
#include <hip/hip_runtime.h>
#include <stdint.h>

typedef unsigned short u16;
typedef unsigned int u32;
typedef unsigned long long u64;
typedef __attribute__((ext_vector_type(4))) float f32x4;
typedef __attribute__((ext_vector_type(8))) short bf16x8;
typedef __attribute__((ext_vector_type(4))) u32 u32x4;

constexpr int kT = 8192;   // sequence length
constexpr int kD = 512;    // word emb dim
constexpr int kH = 2048;   // hidden
constexpr int kH3 = 6144;  // 3*H
constexpr int kS = 512;    // segments
constexpr int kSeg = 16;   // tokens per segment
constexpr int kNWG2 = 256; // persistent WGs for upper GRU
constexpr int kREP = 4;    // h-exchange replicas

__device__ __forceinline__ float bf2f(u16 u) {
  union { float f; u32 u; } v; v.u = ((u32)u) << 16; return v.f;
}
__device__ __forceinline__ u16 f2bf(float f) {
  union { float f; u32 u; } v; v.f = f;
  u32 lsb = (v.u >> 16) & 1u;
  v.u += 0x7fffu + lsb;          // round-to-nearest-even
  return (u16)(v.u >> 16);
}
// cheap packed-bf16 unpack: lo/hi half of a u32 as f32 (2 ops each)
__device__ __forceinline__ float bflo(u32 x) {
  union { float f; u32 u; } v; v.u = x << 16; return v.f;
}
__device__ __forceinline__ float bfhi(u32 x) {
  union { float f; u32 u; } v; v.u = x & 0xffff0000u; return v.f;
}
__device__ __forceinline__ float sigm(float x) { return 1.f / (1.f + expf(-x)); }

// async global->LDS, 16B per lane; LDS dest = wave-uniform base + lane*16
__device__ __forceinline__ void g2l16(const u16* g, u16* l) {
  __builtin_amdgcn_global_load_lds(
      (const __attribute__((address_space(1))) u32*)g,
      (__attribute__((address_space(3))) u32*)l, 16, 0, 0);
}

// device-coherent (sc0 sc1) 16B bypass load/store
__device__ __forceinline__ u32x4 bypass_load16(const u32* p) {
  u32x4 v;
  asm volatile("global_load_dwordx4 %0, %1, off sc0 sc1\n\ts_waitcnt vmcnt(0)"
               : "=&v"(v) : "v"(p) : "memory");
  return v;
}
__device__ __forceinline__ void bypass_store16(u32* p, u32x4 v) {
  asm volatile("global_store_dwordx4 %0, %1, off sc0 sc1" :: "v"(p), "v"(v) : "memory");
}

// ---------------- f32 -> bf16 convert ----------------
__global__ void cvt_bf16(const float* __restrict__ in, u16* __restrict__ out, int n4) {
  int i = blockIdx.x * blockDim.x + threadIdx.x;
  if (i >= n4) return;
  const float4 v = *(const float4*)(in + (size_t)i * 4);
  uint2 o;
  o.x = (u32)f2bf(v.x) | ((u32)f2bf(v.y) << 16);
  o.y = (u32)f2bf(v.z) | ((u32)f2bf(v.w) << 16);
  *(uint2*)(out + (size_t)i * 4) = o;
}

// ---------------- bf16 GEMM  C = A(MxK,lda) * B(NxK,ldb)^T ----------------
// 4-deep software-pipelined staging (counted vmcnt + raw s_barrier; never
// drain-0 mid-loop). EPI 1: Obf = bf16(acc)   EPI 2: Obf = bf16(tanh(acc+bias))
template<int EPI>
__global__ __launch_bounds__(256)
void gemm_bt(const u16* __restrict__ A, int lda,
             const u16* __restrict__ B, int ldb,
             u16* __restrict__ Obf, const float* __restrict__ bias,
             int M, int N, int K)
{
  __shared__ u16 ls[4 * 16384];   // 4 bufs x (A 128x64 + B 128x64) = 128 KiB
  const int tid = threadIdx.x;
  const int w = tid >> 6, lane = tid & 63;
  const int wr = w >> 1, wc = w & 1;
  const int arow0 = blockIdx.y * 128;
  const int brow0 = blockIdx.x * 128;
  const int srow = w * 32 + (lane >> 3);
  const int scol = (lane & 7) * 8;
  const u16* gA = A + (size_t)(arow0 + srow) * lda + scol;
  const u16* gB = B + (size_t)(brow0 + srow) * ldb + scol;
  const int sb = w * 32 * 64;     // wave's staging base (rows w*32..)

  f32x4 acc[4][4];
#pragma unroll
  for (int m = 0; m < 4; ++m)
#pragma unroll
    for (int n = 0; n < 4; ++n) acc[m][n] = (f32x4)0.f;

  const int fr = lane & 15;
  const int kq = lane >> 4;
  const int nk = K >> 6;

  auto stage = [&](int buf, int kt) {
    u16* la = &ls[buf * 16384 + sb];
    u16* lb = &ls[buf * 16384 + 8192 + sb];
#pragma unroll
    for (int i = 0; i < 4; ++i) g2l16(gA + (size_t)i * 8 * lda + kt, la + i * 8 * 64);
#pragma unroll
    for (int i = 0; i < 4; ++i) g2l16(gB + (size_t)i * 8 * ldb + kt, lb + i * 8 * 64);
  };

  stage(0, 0);
  if (nk > 1) stage(1, 64);
  if (nk > 2) stage(2, 128);

  for (int i = 0; i < nk; ++i) {
    if (i + 2 < nk) asm volatile("s_waitcnt vmcnt(16)" ::: "memory");
    else            asm volatile("s_waitcnt vmcnt(0)" ::: "memory");
    __builtin_amdgcn_s_barrier();
    __builtin_amdgcn_sched_barrier(0);
    if (i + 3 < nk) stage((i + 3) & 3, (i + 3) * 64);
    const u16* lsA = &ls[(i & 3) * 16384];
    const u16* lsB = lsA + 8192;
#pragma unroll
    for (int kk = 0; kk < 2; ++kk) {
      bf16x8 af[4], bq[4];
#pragma unroll
      for (int m = 0; m < 4; ++m)
        af[m] = *(const bf16x8*)&lsA[(wr * 64 + m * 16 + fr) * 64 + kk * 32 + kq * 8];
#pragma unroll
      for (int n = 0; n < 4; ++n)
        bq[n] = *(const bf16x8*)&lsB[(wc * 64 + n * 16 + fr) * 64 + kk * 32 + kq * 8];
#pragma unroll
      for (int m = 0; m < 4; ++m)
#pragma unroll
        for (int n = 0; n < 4; ++n)
          acc[m][n] = __builtin_amdgcn_mfma_f32_16x16x32_bf16(af[m], bq[n], acc[m][n], 0, 0, 0);
    }
  }

#pragma unroll
  for (int m = 0; m < 4; ++m) {
#pragma unroll
    for (int n = 0; n < 4; ++n) {
      const int row0 = arow0 + wr * 64 + m * 16 + kq * 4;
      const int col = brow0 + wc * 64 + n * 16 + fr;
      if (EPI == 1) {
#pragma unroll
        for (int i = 0; i < 4; ++i)
          Obf[(size_t)(row0 + i) * N + col] = f2bf(acc[m][n][i]);
      } else {
        const float bv = bias[col];
#pragma unroll
        for (int i = 0; i < 4; ++i)
          Obf[(size_t)(row0 + i) * N + col] = f2bf(tanhf(acc[m][n][i] + bv));
      }
    }
  }
}

// ---------------- lower-GRU gates, paired-u32 bf16 I/O ----------------
// gi32: base pointer (already offset for this step), segStride in u32 words.
__global__ __launch_bounds__(256) void gru1_gates(
    const u32* __restrict__ gi32, int segStride, const u16* __restrict__ gh,
    const float* __restrict__ bi, const float* __restrict__ bh,
    u16* __restrict__ h_bf, u16* __restrict__ outs_bf, int t)
{
  const int idx = blockIdx.x * 256 + threadIdx.x;  // 512*1024 pairs
  const int seg = idx >> 10, jp = idx & 1023;      // j = 2*jp
  const u32* gh32 = (const u32*)gh;
  const int gbase = seg * segStride;
  const int base = seg * 3072;
  const u32 gir = gi32[gbase + jp],        ghr = gh32[base + jp];
  const u32 giz = gi32[gbase + 1024 + jp], ghz = gh32[base + 1024 + jp];
  const u32 gin = gi32[gbase + 2048 + jp], ghn = gh32[base + 2048 + jp];
  const float2 bir = *(const float2*)&bi[2 * jp];
  const float2 biz = *(const float2*)&bi[kH + 2 * jp];
  const float2 bin = *(const float2*)&bi[2 * kH + 2 * jp];
  const float2 bhr = *(const float2*)&bh[2 * jp];
  const float2 bhz = *(const float2*)&bh[kH + 2 * jp];
  const float2 bhn = *(const float2*)&bh[2 * kH + 2 * jp];
  const u32 hp = ((const u32*)h_bf)[seg * 1024 + jp];
  float hn[2];
#pragma unroll
  for (int e = 0; e < 2; ++e) {
    const float gr = e ? bfhi(gir) : bflo(gir), hr = e ? bfhi(ghr) : bflo(ghr);
    const float gz = e ? bfhi(giz) : bflo(giz), hz = e ? bfhi(ghz) : bflo(ghz);
    const float gn = e ? bfhi(gin) : bflo(gin), hh = e ? bfhi(ghn) : bflo(ghn);
    const float r = sigm(gr + (e ? bir.y : bir.x) + hr + (e ? bhr.y : bhr.x));
    const float z = sigm(gz + (e ? biz.y : biz.x) + hz + (e ? bhz.y : bhz.x));
    const float n = tanhf(gn + (e ? bin.y : bin.x) + r * (hh + (e ? bhn.y : bhn.x)));
    const float hprev = e ? bfhi(hp) : bflo(hp);
    hn[e] = (1.f - z) * n + z * hprev;
  }
  const u32 packed = (u32)f2bf(hn[0]) | ((u32)f2bf(hn[1]) << 16);
  ((u32*)h_bf)[seg * 1024 + jp] = packed;
  ((u32*)outs_bf)[(size_t)(seg * kSeg + t) * 1024 + jp] = packed;
}

// ---------------- degenerate softmax weight + per-segment column max ----------------
__global__ __launch_bounds__(256) void seg_weight_max(
    const u16* __restrict__ embh, const float* __restrict__ wa,
    u16* __restrict__ seg_bf)
{
  __shared__ float wrow[16];
  const int s = blockIdx.x, tid = threadIdx.x;
  const int w = tid >> 6, lane = tid & 63;
#pragma unroll
  for (int rr = 0; rr < 4; ++rr) {
    const int r = w * 4 + rr;
    const u16* row = embh + ((size_t)s * kSeg + r) * kH;
    float p = 0.f;
#pragma unroll
    for (int k = 0; k < 32; ++k) {
      const int c = lane + 64 * k;
      p += bf2f(row[c]) * wa[c];
    }
#pragma unroll
    for (int off = 32; off; off >>= 1) p += __shfl_down(p, off, 64);
    if (lane == 0) { const float e = expf(p); wrow[r] = e / (e + 1e-4f); }
  }
  __syncthreads();
#pragma unroll
  for (int i = 0; i < 8; ++i) {
    const int c = tid + 256 * i;
    float m = -1e30f;
#pragma unroll
    for (int r = 0; r < 16; ++r)
      m = fmaxf(m, wrow[r] * bf2f(embh[((size_t)s * kSeg + r) * kH + c]));
    seg_bf[(size_t)s * kH + c] = f2bf(m);
  }
}

// ---------------- upper GRU: persistent, 512 steps -------------------------
// Self-validating exchange words: u32 = (bf16 << 16) | step_tag.
// PREDICATED RE-POLL: after the mandatory first load, only lanes whose tag is
// stale re-issue loads (each lane's quad belongs to exactly one producer).
// Cuts steady-state sc0/sc1 poll traffic ~10-30x (congestion hypothesis A/B).
__global__ __launch_bounds__(512)
void gru2_persistent(const u16* __restrict__ Wh2bf, const u16* __restrict__ gi2b,
                     const float* __restrict__ bi2, const float* __restrict__ bh2,
                     u32* __restrict__ hx,        // [2][kREP][2048] tagged u32
                     u16* __restrict__ outs2)     // 512*2048 bf16
{
  __shared__ u16 wl[24 * kH];                 // 96 KiB weights (24 rows)
  __shared__ u32 hlb[1024];                   // 4 KiB: h as packed bf16 pairs
  __shared__ float gil_all[512 * 24];         // 48 KiB gi2 slice
  __shared__ float rowsum[24];
  __shared__ alignas(16) u16 hnl[8];
  const int wg = blockIdx.x, tid = threadIdx.x;
  const int g0 = wg * 8;
  const int rep = wg & (kREP - 1);
  // weights: 24 rows x 256 uint4
  uint4* wl4 = (uint4*)wl;
  for (int i = tid; i < 24 * 256; i += 512) {
    const int lr = i >> 8, q = i & 255;
    const int grow = (lr >> 3) * kH + g0 + (lr & 7);
    wl4[i] = ((const uint4*)Wh2bf)[(size_t)grow * 256 + q];
  }
  for (int i = tid; i < 512 * 24; i += 512) {
    const int t = i / 24, idx = i - t * 24;
    gil_all[i] = bf2f(gi2b[(size_t)t * kH3 + (idx >> 3) * kH + g0 + (idx & 7)]);
  }
  float bir = 0, biz = 0, bin = 0, bhr = 0, bhz = 0, bhn = 0;
  if (tid < 8) {
    const int jj = g0 + tid;
    bir = bi2[jj]; biz = bi2[kH + jj]; bin = bi2[2 * kH + jj];
    bhr = bh2[jj]; bhz = bh2[kH + jj]; bhn = bh2[2 * kH + jj];
  }
  const int w = tid >> 6, lane = tid & 63;
  const uint4* hl4 = (const uint4*)hlb;

  for (int t = 0; t < 512; ++t) {
    // ---- poll-in: mandatory first load, predicated re-poll of stale lanes ----
    const u32 want = (u32)t & 0xffffu;
    const u32* p = hx + ((size_t)(t & 1) * kREP + rep) * 2048 + 4 * tid;
    u32x4 v = bypass_load16(p);
    for (;;) {
      const u32 bad = ((v.x ^ want) | (v.y ^ want) | (v.z ^ want) | (v.w ^ want)) & 0xffffu;
      if (!__any((int)bad)) break;
      if (bad) {
        __builtin_amdgcn_s_sleep(2);
        v = bypass_load16(p);
      }
    }
    hlb[2 * tid]     = (v.x >> 16) | (v.y & 0xffff0000u);
    hlb[2 * tid + 1] = (v.z >> 16) | (v.w & 0xffff0000u);
    __syncthreads();
    // ---- matvec: 3 rows per wave, uint4 LDS reads, 2-op unpack ----
#pragma unroll
    for (int rr = 0; rr < 3; ++rr) {
      const int lr = w * 3 + rr;
      float p2 = 0.f;
#pragma unroll
      for (int k = 0; k < 4; ++k) {
        const int q = lane + 64 * k;
        const uint4 wv = wl4[lr * 256 + q];
        const uint4 hv = hl4[q];
        p2 += bflo(wv.x) * bflo(hv.x) + bfhi(wv.x) * bfhi(hv.x);
        p2 += bflo(wv.y) * bflo(hv.y) + bfhi(wv.y) * bfhi(hv.y);
        p2 += bflo(wv.z) * bflo(hv.z) + bfhi(wv.z) * bfhi(hv.z);
        p2 += bflo(wv.w) * bflo(hv.w) + bfhi(wv.w) * bfhi(hv.w);
      }
#pragma unroll
      for (int off = 32; off; off >>= 1) p2 += __shfl_down(p2, off, 64);
      if (lane == 0) rowsum[lr] = p2;
    }
    __syncthreads();
    // ---- gates ----
    if (tid < 8) {
      const float r = sigm(gil_all[t * 24 + tid] + bir + rowsum[tid] + bhr);
      const float z = sigm(gil_all[t * 24 + 8 + tid] + biz + rowsum[8 + tid] + bhz);
      const float n = tanhf(gil_all[t * 24 + 16 + tid] + bin +
                            r * (rowsum[16 + tid] + bhn));
      const u32 hw = hlb[(g0 + tid) >> 1];
      const float hprev = (tid & 1) ? bfhi(hw) : bflo(hw);
      hnl[tid] = f2bf((1.f - z) * n + z * hprev);
    }
    __syncthreads();
    // ---- tagged broadcast-out: 2 x 16B per replica, 8 threads total ----
    if (tid < 2 * kREP) {
      const int orep = tid >> 1, half = tid & 1;
      const u16* h4 = hnl + half * 4;
      const u32 tagv = (u32)(t + 1) & 0xffffu;
      u32x4 m;
      m.x = ((u32)h4[0] << 16) | tagv;
      m.y = ((u32)h4[1] << 16) | tagv;
      m.z = ((u32)h4[2] << 16) | tagv;
      m.w = ((u32)h4[3] << 16) | tagv;
      u32* q = hx + ((size_t)((t + 1) & 1) * kREP + orep) * 2048 + wg * 8 + half * 4;
      bypass_store16(q, m);
    }
    if (tid == 0)
      *(uint4*)&outs2[(size_t)t * kH + g0] = *(const uint4*)hnl;
  }
}

// ---------------- w2 then final column max ----------------
__global__ void calc_w2(const u16* __restrict__ e2, const float* __restrict__ wa2,
                        float* __restrict__ w2) {
  const int s = blockIdx.x, lane = threadIdx.x;  // 64 threads
  float p = 0.f;
#pragma unroll
  for (int k = 0; k < 32; ++k) {
    const int c = lane + 64 * k;
    p += bf2f(e2[(size_t)s * kH + c]) * wa2[c];
  }
#pragma unroll
  for (int off = 32; off; off >>= 1) p += __shfl_down(p, off, 64);
  if (lane == 0) { const float e = expf(p); w2[s] = e / (e + 1e-4f); }
}

__global__ void final_max(const u16* __restrict__ e2, const float* __restrict__ w2,
                          float* __restrict__ out) {
  const int j = blockIdx.x * blockDim.x + threadIdx.x;  // 2048
  float m = -1e30f;
  for (int s = 0; s < 512; ++s)
    m = fmaxf(m, w2[s] * bf2f(e2[(size_t)s * kH + j]));
  out[j] = m;
}

// ---------------- host ----------------
extern "C" void kernel_launch(void* const* d_in, const int* in_sizes, int n_in,
                              void* d_out, int out_size, void* d_ws, size_t ws_size,
                              hipStream_t stream)
{
  (void)in_sizes; (void)n_in; (void)out_size;
  const float* sent = (const float*)d_in[0];
  const float* Wi1f = (const float*)d_in[1];
  const float* Wh1f = (const float*)d_in[2];
  const float* bi1  = (const float*)d_in[3];
  const float* bh1  = (const float*)d_in[4];
  const float* Wi2f = (const float*)d_in[5];
  const float* Wh2f = (const float*)d_in[6];
  const float* bi2  = (const float*)d_in[7];
  const float* bh2  = (const float*)d_in[8];
  const float* Wlf  = (const float*)d_in[9];
  const float* bl   = (const float*)d_in[10];
  const float* wa   = (const float*)d_in[11];
  const float* Wl2f = (const float*)d_in[12];
  const float* bl2  = (const float*)d_in[13];
  const float* wa2  = (const float*)d_in[14];
  float* out = (float*)d_out;

  char* base = (char*)d_ws;
  size_t off = 0;
  auto alloc = [&](size_t b) { char* p = base + off; off += (b + 255) & ~(size_t)255; return p; };
  u16* sent_bf = (u16*)alloc((size_t)kT * kD * 2);   // dead after GI/phase B -> embh alias
  u16* Wi1b    = (u16*)alloc((size_t)kH3 * kD * 2);
  u16* Wh1b    = (u16*)alloc((size_t)kH3 * kH * 2);
  u16* Wi2b    = (u16*)alloc((size_t)kH3 * kH * 2);
  u16* Wh2b    = (u16*)alloc((size_t)kH3 * kH * 2);
  u16* Wlb     = (u16*)alloc((size_t)kH * kH * 2);
  u16* Wl2b    = (u16*)alloc((size_t)kH * kH * 2);
  u16* gi_buf  = (u16*)alloc((size_t)kS * kH3 * 2);  // per-step fallback
  u16* gh_buf  = (u16*)alloc((size_t)kS * kH3 * 2);
  u16* h1b     = (u16*)alloc((size_t)kS * kH * 2);
  u16* outs_bf = (u16*)alloc((size_t)kT * kH * 2);
  u16* seg_bf  = (u16*)alloc((size_t)kS * kH * 2);
  u32* hx      = (u32*)alloc((size_t)2 * kREP * 2048 * 4);
  u16* outs2   = (u16*)alloc((size_t)kS * kH * 2);
  u16* e2b     = (u16*)alloc((size_t)kS * kH * 2);
  float* w2    = (float*)alloc(kS * 4);
  // optional fused-gi buffer (100.7 MB): engage only if ws is big enough
  const size_t off_before_gi = off;
  u16* gi_all  = (u16*)alloc((size_t)kT * kH3 * 2);
  const bool fused_gi = (off <= ws_size);
  if (!fused_gi) off = off_before_gi;
  // aliases over dead regions
  u16* embh = sent_bf;   // 33.5 MB fits in sent_bf+Wi1b+Wh1b (39.8 MB)
  u16* gi2b = gi_buf;

  (void)hipMemsetAsync(h1b, 0, (size_t)kS * kH * 2, stream);
  (void)hipMemsetAsync(hx, 0, (size_t)2 * kREP * 2048 * 4, stream);

  auto cvt = [&](const float* src, u16* dst, int n) {
    const int n4 = n / 4;
    cvt_bf16<<<dim3((n4 + 255) / 256), dim3(256), 0, stream>>>(src, dst, n4);
  };
  cvt(sent, sent_bf, kT * kD);
  cvt(Wi1f, Wi1b, kH3 * kD);
  cvt(Wh1f, Wh1b, kH3 * kH);
  cvt(Wi2f, Wi2b, kH3 * kH);
  cvt(Wlf, Wlb, kH * kH);
  cvt(Wl2f, Wl2b, kH * kH);
  cvt(Wh2f, Wh2b, kH3 * kH);

  // ---- phase B: lower GRU, 16 batched steps over 512 independent chains ----
  if (fused_gi) {
    // one big GI GEMM for all 16 steps: (8192 x 6144 x 512), 3072 blocks
    gemm_bt<1><<<dim3(kH3 / 128, kT / 128), dim3(256), 0, stream>>>(
        sent_bf, kD, Wi1b, kD, gi_all, nullptr, kT, kH3, kD);
  }
  for (int t = 0; t < kSeg; ++t) {
    gemm_bt<1><<<dim3(kH3 / 128, kS / 128), dim3(256), 0, stream>>>(
        h1b, kH, Wh1b, kH, gh_buf, nullptr, kS, kH3, kH);
    const u32* gi32;
    int segStride;
    if (fused_gi) {
      gi32 = (const u32*)gi_all + (size_t)t * 3072;   // token = seg*16 + t
      segStride = kSeg * 3072;
    } else {
      gemm_bt<1><<<dim3(kH3 / 128, kS / 128), dim3(256), 0, stream>>>(
          sent_bf + t * kD, kSeg * kD, Wi1b, kD, gi_buf, nullptr, kS, kH3, kD);
      gi32 = (const u32*)gi_buf;
      segStride = 3072;
    }
    gru1_gates<<<dim3(kS * kH / 512), dim3(256), 0, stream>>>(
        gi32, segStride, gh_buf, bi1, bh1, h1b, outs_bf, t);
  }
  // ---- phase C: emb_h = tanh(outs @ Wl^T + bl) ----
  gemm_bt<2><<<dim3(kH / 128, kT / 128), dim3(256), 0, stream>>>(
      outs_bf, kH, Wlb, kH, embh, bl, kT, kH, kH);
  // ---- phase D: w, weighted, segment max ----
  seg_weight_max<<<dim3(kS), dim3(256), 0, stream>>>(embh, wa, seg_bf);
  // ---- phase E: gi2 = seg @ Wi2^T (bf16) ----
  gemm_bt<1><<<dim3(kH3 / 128, kS / 128), dim3(256), 0, stream>>>(
      seg_bf, kH, Wi2b, kH, gi2b, nullptr, kS, kH3, kH);
  // ---- phase F: upper GRU, 512 sequential steps, self-validating exchange ----
  gru2_persistent<<<dim3(kNWG2), dim3(512), 0, stream>>>(
      Wh2b, gi2b, bi2, bh2, hx, outs2);
  // ---- phase G: e2 = tanh(outs2 @ Wl2^T + bl2), w2, final max ----
  gemm_bt<2><<<dim3(kH / 128, kS / 128), dim3(256), 0, stream>>>(
      outs2, kH, Wl2b, kH, e2b, bl2, kS, kH, kH);
  calc_w2<<<dim3(kS), dim3(64), 0, stream>>>(e2b, wa2, w2);
  final_max<<<dim3(kH / 256), dim3(256), 0, stream>>>(e2b, w2, out);
}

// Round 7
// 2510.386 us; speedup vs baseline: 1.1867x; 1.1839x over previous
//
#include <hip/hip_runtime.h>
#include <stdint.h>

typedef unsigned short u16;
typedef unsigned int u32;
typedef unsigned long long u64;
typedef __attribute__((ext_vector_type(4))) float f32x4;
typedef __attribute__((ext_vector_type(8))) short bf16x8;
typedef __attribute__((ext_vector_type(4))) u32 u32x4;

constexpr int kT = 8192;   // sequence length
constexpr int kD = 512;    // word emb dim
constexpr int kH = 2048;   // hidden
constexpr int kH3 = 6144;  // 3*H
constexpr int kS = 512;    // segments
constexpr int kSeg = 16;   // tokens per segment
constexpr int kNWG2 = 256; // persistent WGs for upper GRU
constexpr int kREP = 4;    // h-exchange replicas

__device__ __forceinline__ float bf2f(u16 u) {
  union { float f; u32 u; } v; v.u = ((u32)u) << 16; return v.f;
}
__device__ __forceinline__ u16 f2bf(float f) {
  union { float f; u32 u; } v; v.f = f;
  u32 lsb = (v.u >> 16) & 1u;
  v.u += 0x7fffu + lsb;          // round-to-nearest-even
  return (u16)(v.u >> 16);
}
// cheap packed-bf16 unpack: lo/hi half of a u32 as f32 (2 ops each)
__device__ __forceinline__ float bflo(u32 x) {
  union { float f; u32 u; } v; v.u = x << 16; return v.f;
}
__device__ __forceinline__ float bfhi(u32 x) {
  union { float f; u32 u; } v; v.u = x & 0xffff0000u; return v.f;
}
__device__ __forceinline__ float sigm(float x) { return 1.f / (1.f + expf(-x)); }

// async global->LDS, 16B per lane; LDS dest = wave-uniform base + lane*16
__device__ __forceinline__ void g2l16(const u16* g, u16* l) {
  __builtin_amdgcn_global_load_lds(
      (const __attribute__((address_space(1))) u32*)g,
      (__attribute__((address_space(3))) u32*)l, 16, 0, 0);
}

// device-coherent (sc0 sc1) 16B bypass load/store
__device__ __forceinline__ u32x4 bypass_load16(const u32* p) {
  u32x4 v;
  asm volatile("global_load_dwordx4 %0, %1, off sc0 sc1\n\ts_waitcnt vmcnt(0)"
               : "=&v"(v) : "v"(p) : "memory");
  return v;
}
__device__ __forceinline__ void bypass_store16(u32* p, u32x4 v) {
  asm volatile("global_store_dwordx4 %0, %1, off sc0 sc1" :: "v"(p), "v"(v) : "memory");
}

// ---------------- f32 -> bf16 convert ----------------
__global__ void cvt_bf16(const float* __restrict__ in, u16* __restrict__ out, int n4) {
  int i = blockIdx.x * blockDim.x + threadIdx.x;
  if (i >= n4) return;
  const float4 v = *(const float4*)(in + (size_t)i * 4);
  uint2 o;
  o.x = (u32)f2bf(v.x) | ((u32)f2bf(v.y) << 16);
  o.y = (u32)f2bf(v.z) | ((u32)f2bf(v.w) << 16);
  *(uint2*)(out + (size_t)i * 4) = o;
}

// ---------------- bf16 GEMM  C = A(MxK,lda) * B(NxK,ldb)^T ----------------
// 4-deep software-pipelined staging (counted vmcnt + raw s_barrier; never
// drain-0 mid-loop). EPI 1: Obf = bf16(acc)   EPI 2: Obf = bf16(tanh(acc+bias))
template<int EPI>
__global__ __launch_bounds__(256)
void gemm_bt(const u16* __restrict__ A, int lda,
             const u16* __restrict__ B, int ldb,
             u16* __restrict__ Obf, const float* __restrict__ bias,
             int M, int N, int K)
{
  __shared__ u16 ls[4 * 16384];   // 4 bufs x (A 128x64 + B 128x64) = 128 KiB
  const int tid = threadIdx.x;
  const int w = tid >> 6, lane = tid & 63;
  const int wr = w >> 1, wc = w & 1;
  const int arow0 = blockIdx.y * 128;
  const int brow0 = blockIdx.x * 128;
  const int srow = w * 32 + (lane >> 3);
  const int scol = (lane & 7) * 8;
  const u16* gA = A + (size_t)(arow0 + srow) * lda + scol;
  const u16* gB = B + (size_t)(brow0 + srow) * ldb + scol;
  const int sb = w * 32 * 64;     // wave's staging base (rows w*32..)

  f32x4 acc[4][4];
#pragma unroll
  for (int m = 0; m < 4; ++m)
#pragma unroll
    for (int n = 0; n < 4; ++n) acc[m][n] = (f32x4)0.f;

  const int fr = lane & 15;
  const int kq = lane >> 4;
  const int nk = K >> 6;

  auto stage = [&](int buf, int kt) {
    u16* la = &ls[buf * 16384 + sb];
    u16* lb = &ls[buf * 16384 + 8192 + sb];
#pragma unroll
    for (int i = 0; i < 4; ++i) g2l16(gA + (size_t)i * 8 * lda + kt, la + i * 8 * 64);
#pragma unroll
    for (int i = 0; i < 4; ++i) g2l16(gB + (size_t)i * 8 * ldb + kt, lb + i * 8 * 64);
  };

  stage(0, 0);
  if (nk > 1) stage(1, 64);
  if (nk > 2) stage(2, 128);

  for (int i = 0; i < nk; ++i) {
    if (i + 2 < nk) asm volatile("s_waitcnt vmcnt(16)" ::: "memory");
    else            asm volatile("s_waitcnt vmcnt(0)" ::: "memory");
    __builtin_amdgcn_s_barrier();
    __builtin_amdgcn_sched_barrier(0);
    if (i + 3 < nk) stage((i + 3) & 3, (i + 3) * 64);
    const u16* lsA = &ls[(i & 3) * 16384];
    const u16* lsB = lsA + 8192;
#pragma unroll
    for (int kk = 0; kk < 2; ++kk) {
      bf16x8 af[4], bq[4];
#pragma unroll
      for (int m = 0; m < 4; ++m)
        af[m] = *(const bf16x8*)&lsA[(wr * 64 + m * 16 + fr) * 64 + kk * 32 + kq * 8];
#pragma unroll
      for (int n = 0; n < 4; ++n)
        bq[n] = *(const bf16x8*)&lsB[(wc * 64 + n * 16 + fr) * 64 + kk * 32 + kq * 8];
#pragma unroll
      for (int m = 0; m < 4; ++m)
#pragma unroll
        for (int n = 0; n < 4; ++n)
          acc[m][n] = __builtin_amdgcn_mfma_f32_16x16x32_bf16(af[m], bq[n], acc[m][n], 0, 0, 0);
    }
  }

#pragma unroll
  for (int m = 0; m < 4; ++m) {
#pragma unroll
    for (int n = 0; n < 4; ++n) {
      const int row0 = arow0 + wr * 64 + m * 16 + kq * 4;
      const int col = brow0 + wc * 64 + n * 16 + fr;
      if (EPI == 1) {
#pragma unroll
        for (int i = 0; i < 4; ++i)
          Obf[(size_t)(row0 + i) * N + col] = f2bf(acc[m][n][i]);
      } else {
        const float bv = bias[col];
#pragma unroll
        for (int i = 0; i < 4; ++i)
          Obf[(size_t)(row0 + i) * N + col] = f2bf(tanhf(acc[m][n][i] + bv));
      }
    }
  }
}

// ---------------- lower-GRU gates, paired-u32 bf16 I/O ----------------
// gi32: base pointer (already offset for this step), segStride in u32 words.
// ghvalid==0: h_prev==0 -> Wh*h terms and hprev are zero (t==0 fast path).
__global__ __launch_bounds__(256) void gru1_gates(
    const u32* __restrict__ gi32, int segStride, const u16* __restrict__ gh,
    const float* __restrict__ bi, const float* __restrict__ bh,
    u16* __restrict__ h_bf, u16* __restrict__ outs_bf, int t, int ghvalid)
{
  const int idx = blockIdx.x * 256 + threadIdx.x;  // 512*1024 pairs
  const int seg = idx >> 10, jp = idx & 1023;      // j = 2*jp
  const u32* gh32 = (const u32*)gh;
  const int gbase = seg * segStride;
  const int base = seg * 3072;
  const u32 gir = gi32[gbase + jp];
  const u32 giz = gi32[gbase + 1024 + jp];
  const u32 gin = gi32[gbase + 2048 + jp];
  u32 ghr = 0, ghz = 0, ghn = 0, hp = 0;
  if (ghvalid) {
    ghr = gh32[base + jp];
    ghz = gh32[base + 1024 + jp];
    ghn = gh32[base + 2048 + jp];
    hp = ((const u32*)h_bf)[seg * 1024 + jp];
  }
  const float2 bir = *(const float2*)&bi[2 * jp];
  const float2 biz = *(const float2*)&bi[kH + 2 * jp];
  const float2 bin = *(const float2*)&bi[2 * kH + 2 * jp];
  const float2 bhr = *(const float2*)&bh[2 * jp];
  const float2 bhz = *(const float2*)&bh[kH + 2 * jp];
  const float2 bhn = *(const float2*)&bh[2 * kH + 2 * jp];
  float hn[2];
#pragma unroll
  for (int e = 0; e < 2; ++e) {
    const float gr = e ? bfhi(gir) : bflo(gir), hr = e ? bfhi(ghr) : bflo(ghr);
    const float gz = e ? bfhi(giz) : bflo(giz), hz = e ? bfhi(ghz) : bflo(ghz);
    const float gn = e ? bfhi(gin) : bflo(gin), hh = e ? bfhi(ghn) : bflo(ghn);
    const float r = sigm(gr + (e ? bir.y : bir.x) + hr + (e ? bhr.y : bhr.x));
    const float z = sigm(gz + (e ? biz.y : biz.x) + hz + (e ? bhz.y : bhz.x));
    const float n = tanhf(gn + (e ? bin.y : bin.x) + r * (hh + (e ? bhn.y : bhn.x)));
    const float hprev = e ? bfhi(hp) : bflo(hp);
    hn[e] = (1.f - z) * n + z * hprev;
  }
  const u32 packed = (u32)f2bf(hn[0]) | ((u32)f2bf(hn[1]) << 16);
  ((u32*)h_bf)[seg * 1024 + jp] = packed;
  ((u32*)outs_bf)[(size_t)(seg * kSeg + t) * 1024 + jp] = packed;
}

// ---------------- degenerate softmax weight + per-segment column max ----------------
__global__ __launch_bounds__(256) void seg_weight_max(
    const u16* __restrict__ embh, const float* __restrict__ wa,
    u16* __restrict__ seg_bf)
{
  __shared__ float wrow[16];
  const int s = blockIdx.x, tid = threadIdx.x;
  const int w = tid >> 6, lane = tid & 63;
#pragma unroll
  for (int rr = 0; rr < 4; ++rr) {
    const int r = w * 4 + rr;
    const u16* row = embh + ((size_t)s * kSeg + r) * kH;
    float p = 0.f;
#pragma unroll
    for (int k = 0; k < 32; ++k) {
      const int c = lane + 64 * k;
      p += bf2f(row[c]) * wa[c];
    }
#pragma unroll
    for (int off = 32; off; off >>= 1) p += __shfl_down(p, off, 64);
    if (lane == 0) { const float e = expf(p); wrow[r] = e / (e + 1e-4f); }
  }
  __syncthreads();
#pragma unroll
  for (int i = 0; i < 8; ++i) {
    const int c = tid + 256 * i;
    float m = -1e30f;
#pragma unroll
    for (int r = 0; r < 16; ++r)
      m = fmaxf(m, wrow[r] * bf2f(embh[((size_t)s * kSeg + r) * kH + c]));
    seg_bf[(size_t)s * kH + c] = f2bf(m);
  }
}

// ---------------- upper GRU: persistent, 512 steps -------------------------
// v3: REGISTER-RESIDENT Wh2 matvec. Each lane holds 3 rows x 32 cols of Wh2
// (48 packed u32 VGPRs, loaded once). h bounces through LDS once per step
// (1 b128 write + 4 b128 reads / thread) instead of 24 b128 reads / wave of
// weights+h. Exchange protocol unchanged from r5/r6 (self-validating tagged
// words, predicated re-poll; sleep removed). Gates + publish in wave 0 only.
__global__ __launch_bounds__(512)
void gru2_persistent(const u16* __restrict__ Wh2bf, const u16* __restrict__ gi2b,
                     const float* __restrict__ bi2, const float* __restrict__ bh2,
                     u32* __restrict__ hx,        // [2][kREP][2048] tagged u32
                     u16* __restrict__ outs2)     // 512*2048 bf16
{
  __shared__ u32 hlb[2][1024];                // 8 KiB: h packed pairs, dbuf
  __shared__ float gil_all[512 * 24];         // 48 KiB gi2 slice
  __shared__ float rowsum[24];
  __shared__ u16 hnl[8];
  const int wg = blockIdx.x, tid = threadIdx.x;
  const int g0 = wg * 8;
  const int rep = wg & (kREP - 1);
  const int w = tid >> 6, lane = tid & 63;

  // ---- weights into registers: 3 rows x 16 packed u32 per lane ----
  u32 w0[16], w1[16], w2r[16];
#pragma unroll
  for (int rr = 0; rr < 3; ++rr) {
    const int lr = w * 3 + rr;
    const int grow = (lr >> 3) * kH + g0 + (lr & 7);
    const u32* src = (const u32*)(Wh2bf + (size_t)grow * kH) + lane * 16;
#pragma unroll
    for (int i = 0; i < 16; ++i) {
      const u32 val = src[i];
      if (rr == 0) w0[i] = val;
      else if (rr == 1) w1[i] = val;
      else w2r[i] = val;
    }
  }
  for (int i = tid; i < 512 * 24; i += 512) {
    const int t = i / 24, idx = i - t * 24;
    gil_all[i] = bf2f(gi2b[(size_t)t * kH3 + (idx >> 3) * kH + g0 + (idx & 7)]);
  }
  float bir = 0, biz = 0, bin = 0, bhr = 0, bhz = 0, bhn = 0;
  if (tid < 8) {
    const int jj = g0 + tid;
    bir = bi2[jj]; biz = bi2[kH + jj]; bin = bi2[2 * kH + jj];
    bhr = bh2[jj]; bhz = bh2[kH + jj]; bhn = bh2[2 * kH + jj];
  }

  for (int t = 0; t < 512; ++t) {
    const int par = t & 1;
    // ---- poll own quad (4 h elements), predicated immediate re-poll ----
    const u32 want = (u32)t & 0xffffu;
    const u32* p = hx + ((size_t)par * kREP + rep) * 2048 + 4 * tid;
    u32x4 v = bypass_load16(p);
    for (;;) {
      const u32 bad = ((v.x ^ want) | (v.y ^ want) | (v.z ^ want) | (v.w ^ want)) & 0xffffu;
      if (!__any((int)bad)) break;
      if (bad) v = bypass_load16(p);
    }
    hlb[par][2 * tid]     = (v.x >> 16) | (v.y & 0xffff0000u);
    hlb[par][2 * tid + 1] = (v.z >> 16) | (v.w & 0xffff0000u);
    __syncthreads();
    // ---- register matvec: unpack h slice, 3 rows x 32 MAC per lane ----
    const uint4* hp4 = (const uint4*)&hlb[par][0];
    float hf[32];
#pragma unroll
    for (int q = 0; q < 4; ++q) {
      const uint4 hv = hp4[lane * 4 + q];
      hf[8 * q + 0] = bflo(hv.x); hf[8 * q + 1] = bfhi(hv.x);
      hf[8 * q + 2] = bflo(hv.y); hf[8 * q + 3] = bfhi(hv.y);
      hf[8 * q + 4] = bflo(hv.z); hf[8 * q + 5] = bfhi(hv.z);
      hf[8 * q + 6] = bflo(hv.w); hf[8 * q + 7] = bfhi(hv.w);
    }
    float a0 = 0.f, a1 = 0.f, a2 = 0.f;
#pragma unroll
    for (int i = 0; i < 16; ++i) {
      a0 += bflo(w0[i]) * hf[2 * i] + bfhi(w0[i]) * hf[2 * i + 1];
      a1 += bflo(w1[i]) * hf[2 * i] + bfhi(w1[i]) * hf[2 * i + 1];
      a2 += bflo(w2r[i]) * hf[2 * i] + bfhi(w2r[i]) * hf[2 * i + 1];
    }
#pragma unroll
    for (int off = 32; off; off >>= 1) {
      a0 += __shfl_down(a0, off, 64);
      a1 += __shfl_down(a1, off, 64);
      a2 += __shfl_down(a2, off, 64);
    }
    if (lane == 0) {
      rowsum[w * 3 + 0] = a0;
      rowsum[w * 3 + 1] = a1;
      rowsum[w * 3 + 2] = a2;
    }
    __syncthreads();
    // ---- gates + publish: wave 0 only (no further barrier) ----
    if (tid < 8) {
      const float r = sigm(gil_all[t * 24 + tid] + bir + rowsum[tid] + bhr);
      const float z = sigm(gil_all[t * 24 + 8 + tid] + biz + rowsum[8 + tid] + bhz);
      const float n = tanhf(gil_all[t * 24 + 16 + tid] + bin +
                            r * (rowsum[16 + tid] + bhn));
      const u32 hw = hlb[par][(g0 + tid) >> 1];
      const float hprev = (tid & 1) ? bfhi(hw) : bflo(hw);
      hnl[tid] = f2bf((1.f - z) * n + z * hprev);
    }
    if (tid < 2 * kREP) {
      const int orep = tid >> 1, half = tid & 1;
      const u32 tagv = (u32)(t + 1) & 0xffffu;
      u32x4 m;
      m.x = ((u32)hnl[half * 4 + 0] << 16) | tagv;
      m.y = ((u32)hnl[half * 4 + 1] << 16) | tagv;
      m.z = ((u32)hnl[half * 4 + 2] << 16) | tagv;
      m.w = ((u32)hnl[half * 4 + 3] << 16) | tagv;
      u32* q = hx + ((size_t)(1 - par) * kREP + orep) * 2048 + wg * 8 + half * 4;
      bypass_store16(q, m);
    }
    if (tid == 0)
      *(uint4*)&outs2[(size_t)t * kH + g0] = *(const uint4*)hnl;
  }
}

// ---------------- w2 then final column max ----------------
__global__ void calc_w2(const u16* __restrict__ e2, const float* __restrict__ wa2,
                        float* __restrict__ w2) {
  const int s = blockIdx.x, lane = threadIdx.x;  // 64 threads
  float p = 0.f;
#pragma unroll
  for (int k = 0; k < 32; ++k) {
    const int c = lane + 64 * k;
    p += bf2f(e2[(size_t)s * kH + c]) * wa2[c];
  }
#pragma unroll
  for (int off = 32; off; off >>= 1) p += __shfl_down(p, off, 64);
  if (lane == 0) { const float e = expf(p); w2[s] = e / (e + 1e-4f); }
}

__global__ void final_max(const u16* __restrict__ e2, const float* __restrict__ w2,
                          float* __restrict__ out) {
  const int j = blockIdx.x * blockDim.x + threadIdx.x;  // 2048
  float m = -1e30f;
  for (int s = 0; s < 512; ++s)
    m = fmaxf(m, w2[s] * bf2f(e2[(size_t)s * kH + j]));
  out[j] = m;
}

// ---------------- host ----------------
extern "C" void kernel_launch(void* const* d_in, const int* in_sizes, int n_in,
                              void* d_out, int out_size, void* d_ws, size_t ws_size,
                              hipStream_t stream)
{
  (void)in_sizes; (void)n_in; (void)out_size;
  const float* sent = (const float*)d_in[0];
  const float* Wi1f = (const float*)d_in[1];
  const float* Wh1f = (const float*)d_in[2];
  const float* bi1  = (const float*)d_in[3];
  const float* bh1  = (const float*)d_in[4];
  const float* Wi2f = (const float*)d_in[5];
  const float* Wh2f = (const float*)d_in[6];
  const float* bi2  = (const float*)d_in[7];
  const float* bh2  = (const float*)d_in[8];
  const float* Wlf  = (const float*)d_in[9];
  const float* bl   = (const float*)d_in[10];
  const float* wa   = (const float*)d_in[11];
  const float* Wl2f = (const float*)d_in[12];
  const float* bl2  = (const float*)d_in[13];
  const float* wa2  = (const float*)d_in[14];
  float* out = (float*)d_out;

  char* base = (char*)d_ws;
  size_t off = 0;
  auto alloc = [&](size_t b) { char* p = base + off; off += (b + 255) & ~(size_t)255; return p; };
  u16* sent_bf = (u16*)alloc((size_t)kT * kD * 2);   // dead after GI/phase B -> embh alias
  u16* Wi1b    = (u16*)alloc((size_t)kH3 * kD * 2);
  u16* Wh1b    = (u16*)alloc((size_t)kH3 * kH * 2);
  u16* Wi2b    = (u16*)alloc((size_t)kH3 * kH * 2);
  u16* Wh2b    = (u16*)alloc((size_t)kH3 * kH * 2);
  u16* Wlb     = (u16*)alloc((size_t)kH * kH * 2);
  u16* Wl2b    = (u16*)alloc((size_t)kH * kH * 2);
  u16* gi_buf  = (u16*)alloc((size_t)kS * kH3 * 2);  // per-step fallback
  u16* gh_buf  = (u16*)alloc((size_t)kS * kH3 * 2);
  u16* h1b     = (u16*)alloc((size_t)kS * kH * 2);
  u16* outs_bf = (u16*)alloc((size_t)kT * kH * 2);
  u16* seg_bf  = (u16*)alloc((size_t)kS * kH * 2);
  u32* hx      = (u32*)alloc((size_t)2 * kREP * 2048 * 4);
  u16* outs2   = (u16*)alloc((size_t)kS * kH * 2);
  u16* e2b     = (u16*)alloc((size_t)kS * kH * 2);
  float* w2    = (float*)alloc(kS * 4);
  // optional fused-gi buffer (100.7 MB): engage only if ws is big enough
  const size_t off_before_gi = off;
  u16* gi_all  = (u16*)alloc((size_t)kT * kH3 * 2);
  const bool fused_gi = (off <= ws_size);
  if (!fused_gi) off = off_before_gi;
  // aliases over dead regions
  u16* embh = sent_bf;   // 33.5 MB fits in sent_bf+Wi1b+Wh1b (39.8 MB)
  u16* gi2b = gi_buf;

  (void)hipMemsetAsync(hx, 0, (size_t)2 * kREP * 2048 * 4, stream);

  auto cvt = [&](const float* src, u16* dst, int n) {
    const int n4 = n / 4;
    cvt_bf16<<<dim3((n4 + 255) / 256), dim3(256), 0, stream>>>(src, dst, n4);
  };
  cvt(sent, sent_bf, kT * kD);
  cvt(Wi1f, Wi1b, kH3 * kD);
  cvt(Wh1f, Wh1b, kH3 * kH);
  cvt(Wi2f, Wi2b, kH3 * kH);
  cvt(Wlf, Wlb, kH * kH);
  cvt(Wl2f, Wl2b, kH * kH);
  cvt(Wh2f, Wh2b, kH3 * kH);

  // ---- phase B: lower GRU, 16 batched steps over 512 independent chains ----
  if (fused_gi) {
    // one big GI GEMM for all 16 steps: (8192 x 6144 x 512), 3072 blocks
    gemm_bt<1><<<dim3(kH3 / 128, kT / 128), dim3(256), 0, stream>>>(
        sent_bf, kD, Wi1b, kD, gi_all, nullptr, kT, kH3, kD);
  }
  for (int t = 0; t < kSeg; ++t) {
    if (t > 0) {
      gemm_bt<1><<<dim3(kH3 / 128, kS / 128), dim3(256), 0, stream>>>(
          h1b, kH, Wh1b, kH, gh_buf, nullptr, kS, kH3, kH);
    }
    const u32* gi32;
    int segStride;
    if (fused_gi) {
      gi32 = (const u32*)gi_all + (size_t)t * 3072;   // token = seg*16 + t
      segStride = kSeg * 3072;
    } else {
      gemm_bt<1><<<dim3(kH3 / 128, kS / 128), dim3(256), 0, stream>>>(
          sent_bf + t * kD, kSeg * kD, Wi1b, kD, gi_buf, nullptr, kS, kH3, kD);
      gi32 = (const u32*)gi_buf;
      segStride = 3072;
    }
    gru1_gates<<<dim3(kS * kH / 512), dim3(256), 0, stream>>>(
        gi32, segStride, gh_buf, bi1, bh1, h1b, outs_bf, t, t > 0 ? 1 : 0);
  }
  // ---- phase C: emb_h = tanh(outs @ Wl^T + bl) ----
  gemm_bt<2><<<dim3(kH / 128, kT / 128), dim3(256), 0, stream>>>(
      outs_bf, kH, Wlb, kH, embh, bl, kT, kH, kH);
  // ---- phase D: w, weighted, segment max ----
  seg_weight_max<<<dim3(kS), dim3(256), 0, stream>>>(embh, wa, seg_bf);
  // ---- phase E: gi2 = seg @ Wi2^T (bf16) ----
  gemm_bt<1><<<dim3(kH3 / 128, kS / 128), dim3(256), 0, stream>>>(
      seg_bf, kH, Wi2b, kH, gi2b, nullptr, kS, kH3, kH);
  // ---- phase F: upper GRU, 512 sequential steps, register matvec ----
  gru2_persistent<<<dim3(kNWG2), dim3(512), 0, stream>>>(
      Wh2b, gi2b, bi2, bh2, hx, outs2);
  // ---- phase G: e2 = tanh(outs2 @ Wl2^T + bl2), w2, final max ----
  gemm_bt<2><<<dim3(kH / 128, kS / 128), dim3(256), 0, stream>>>(
      outs2, kH, Wl2b, kH, e2b, bl2, kS, kH, kH);
  calc_w2<<<dim3(kS), dim3(64), 0, stream>>>(e2b, wa2, w2);
  final_max<<<dim3(kH / 256), dim3(256), 0, stream>>>(e2b, w2, out);
}